// Round 1
// baseline (11489.190 us; speedup 1.0000x reference)
//
#include <hip/hip_runtime.h>
#include <hip/hip_bf16.h>

#define N_NODES 100000
#define E_EDGES 1600000
#define HID 128
#define LN_EPS 1e-5f
#define BN 64

// ---------------- Edge kernel: proj + curl + atomic segment-sum ----------------
__global__ __launch_bounds__(256)
void edge_kernel(const float* __restrict__ x,
                 const int* __restrict__ eidx,
                 const float* __restrict__ edge_attr,
                 const float* __restrict__ W_proj,
                 const float* __restrict__ b_proj,
                 float* m_i,
                 float* curl)
{
    __shared__ float Wp[HID * 8]; // (128,8) row-major, 4 KB
    for (int i = threadIdx.x; i < HID * 8; i += 256) Wp[i] = W_proj[i];
    __syncthreads();

    int e = blockIdx.x * 256 + threadIdx.x;
    if (e >= E_EDGES) return;

    int r = eidx[e];
    int c = eidx[E_EDGES + e];

    float dx = x[(size_t)c * 130 + 128] - x[(size_t)r * 130 + 128];
    float dy = x[(size_t)c * 130 + 129] - x[(size_t)r * 130 + 129];

    const float4* ea4 = (const float4*)(edge_attr + (size_t)e * HID);

    float acc[8];
#pragma unroll
    for (int j = 0; j < 8; ++j) acc[j] = b_proj[j];

    float* mrow = m_i + (size_t)c * HID;

#pragma unroll 8
    for (int k4 = 0; k4 < 32; ++k4) {
        float4 a = ea4[k4];
        atomicAdd(&mrow[4 * k4 + 0], a.x);
        atomicAdd(&mrow[4 * k4 + 1], a.y);
        atomicAdd(&mrow[4 * k4 + 2], a.z);
        atomicAdd(&mrow[4 * k4 + 3], a.w);
        const float* w = &Wp[k4 * 32]; // rows 4k4..4k4+3, 8 floats each
#pragma unroll
        for (int j = 0; j < 8; ++j)
            acc[j] += a.x * w[j] + a.y * w[8 + j] + a.z * w[16 + j] + a.w * w[24 + j];
    }

    float ndy = -dy;
#pragma unroll
    for (int h = 0; h < 4; ++h) {
        float C = acc[2 * h] * ndy + acc[2 * h + 1] * dx;
        atomicAdd(&curl[(size_t)c * 4 + h], C);
    }
}

// ---------------- Node kernel: gather node_in -> GEMM1 -> LN -> SiLU -> GEMM2 ----------------
// m_i aliases out (each block reads only its own rows into LDS before writing them).
__global__ __launch_bounds__(256)
void node_kernel(const float* __restrict__ x,
                 const float* m_i,
                 const float* __restrict__ curl,
                 const float* __restrict__ u,
                 const int* __restrict__ batch,
                 const float* __restrict__ W1, const float* __restrict__ b1,
                 const float* __restrict__ ln_g, const float* __restrict__ ln_b,
                 const float* __restrict__ W2, const float* __restrict__ b2,
                 float* out)
{
    __shared__ float A[BN][392]; // 64 x 388 node_in tile (padded), ~100 KB
    int tid = threadIdx.x;
    int base = blockIdx.x * BN;

    // Stage node_in = [h_E(128) | m_i(128) | curl(4) | tau(128)]
    for (int idx = tid; idx < BN * 388; idx += 256) {
        int n = idx / 388;
        int k = idx - n * 388;
        int node = base + n;
        float v = 0.f;
        if (node < N_NODES) {
            if (k < 128)       v = x[(size_t)node * 130 + k];
            else if (k < 256)  v = m_i[(size_t)node * 128 + (k - 128)];
            else if (k < 260)  v = curl[(size_t)node * 4 + (k - 256)];
            else               v = u[(size_t)batch[node] * 128 + (k - 260)];
        }
        A[n][k] = v;
    }
    __syncthreads();

    int tx = tid & 31;  // 32 col-groups of 4
    int ty = tid >> 5;  // 8 node-groups of 8

    float acc[8][4];
#pragma unroll
    for (int i = 0; i < 8; ++i)
#pragma unroll
        for (int j = 0; j < 4; ++j) acc[i][j] = 0.f;

    for (int k = 0; k < 388; ++k) {
        float4 b = *(const float4*)(W1 + (size_t)k * 128 + tx * 4);
#pragma unroll
        for (int i = 0; i < 8; ++i) {
            float a = A[ty * 8 + i][k];
            acc[i][0] += a * b.x;
            acc[i][1] += a * b.y;
            acc[i][2] += a * b.z;
            acc[i][3] += a * b.w;
        }
    }

    float4 b1v = *(const float4*)(b1 + tx * 4);
    float4 gv  = *(const float4*)(ln_g + tx * 4);
    float4 bv  = *(const float4*)(ln_b + tx * 4);
    float4 b2v = *(const float4*)(b2 + tx * 4);

    __syncthreads(); // done reading A; reuse its memory for the SiLU'd tile
    float* S = &A[0][0]; // stride 132 floats per node row

#pragma unroll
    for (int i = 0; i < 8; ++i) {
        float h0 = acc[i][0] + b1v.x;
        float h1 = acc[i][1] + b1v.y;
        float h2 = acc[i][2] + b1v.z;
        float h3 = acc[i][3] + b1v.w;
        float s  = h0 + h1 + h2 + h3;
        float ss = h0 * h0 + h1 * h1 + h2 * h2 + h3 * h3;
#pragma unroll
        for (int m = 1; m < 32; m <<= 1) {
            s  += __shfl_xor(s, m);
            ss += __shfl_xor(ss, m);
        }
        float mu  = s * (1.f / 128.f);
        float var = ss * (1.f / 128.f) - mu * mu;
        float inv = rsqrtf(var + LN_EPS);
        h0 = (h0 - mu) * inv * gv.x + bv.x;
        h1 = (h1 - mu) * inv * gv.y + bv.y;
        h2 = (h2 - mu) * inv * gv.z + bv.z;
        h3 = (h3 - mu) * inv * gv.w + bv.w;
        h0 = h0 / (1.f + expf(-h0));
        h1 = h1 / (1.f + expf(-h1));
        h2 = h2 / (1.f + expf(-h2));
        h3 = h3 / (1.f + expf(-h3));
        *(float4*)&S[(size_t)(ty * 8 + i) * 132 + tx * 4] = make_float4(h0, h1, h2, h3);
    }
    __syncthreads();

    float acc2[8][4];
#pragma unroll
    for (int i = 0; i < 8; ++i)
#pragma unroll
        for (int j = 0; j < 4; ++j) acc2[i][j] = 0.f;

    for (int k = 0; k < 128; ++k) {
        float4 b = *(const float4*)(W2 + (size_t)k * 128 + tx * 4);
#pragma unroll
        for (int i = 0; i < 8; ++i) {
            float a = S[(size_t)(ty * 8 + i) * 132 + k];
            acc2[i][0] += a * b.x;
            acc2[i][1] += a * b.y;
            acc2[i][2] += a * b.z;
            acc2[i][3] += a * b.w;
        }
    }

#pragma unroll
    for (int i = 0; i < 8; ++i) {
        int node = base + ty * 8 + i;
        if (node < N_NODES) {
            float4 o = make_float4(acc2[i][0] + b2v.x, acc2[i][1] + b2v.y,
                                   acc2[i][2] + b2v.z, acc2[i][3] + b2v.w);
            *(float4*)(out + (size_t)node * 128 + tx * 4) = o;
        }
    }
}

extern "C" void kernel_launch(void* const* d_in, const int* in_sizes, int n_in,
                              void* d_out, int out_size, void* d_ws, size_t ws_size,
                              hipStream_t stream) {
    const float* x         = (const float*)d_in[0];
    const int*   eidx      = (const int*)d_in[1];
    const float* edge_attr = (const float*)d_in[2];
    const float* u         = (const float*)d_in[3];
    const int*   batch     = (const int*)d_in[4];
    const float* W_proj    = (const float*)d_in[5];
    const float* b_proj    = (const float*)d_in[6];
    const float* W1        = (const float*)d_in[7];
    const float* b1        = (const float*)d_in[8];
    const float* ln_g      = (const float*)d_in[9];
    const float* ln_b      = (const float*)d_in[10];
    const float* W2        = (const float*)d_in[11];
    const float* b2        = (const float*)d_in[12];

    float* out  = (float*)d_out;
    float* m_i  = out;            // accumulate m_i in-place in d_out (same size N*128)
    float* curl = (float*)d_ws;   // N*4 floats = 1.6 MB scratch

    hipMemsetAsync(m_i, 0, (size_t)N_NODES * 128 * sizeof(float), stream);
    hipMemsetAsync(curl, 0, (size_t)N_NODES * 4 * sizeof(float), stream);

    edge_kernel<<<(E_EDGES + 255) / 256, 256, 0, stream>>>(
        x, eidx, edge_attr, W_proj, b_proj, m_i, curl);

    node_kernel<<<(N_NODES + BN - 1) / BN, 256, 0, stream>>>(
        x, m_i, curl, u, batch, W1, b1, ln_g, ln_b, W2, b2, out);
}

// Round 2
// 1272.583 us; speedup vs baseline: 9.0282x; 9.0282x over previous
//
#include <hip/hip_runtime.h>
#include <hip/hip_bf16.h>

#define N_NODES 100000
#define E_EDGES 1600000
#define HID 128
#define LN_EPS 1e-5f
#define BN 64
#define SCAN_CHUNK 1024
#define NB_SCAN ((N_NODES + SCAN_CHUNK - 1) / SCAN_CHUNK)  // 98

// ---------------- CSR build ----------------
__global__ __launch_bounds__(256)
void k_hist(const int* __restrict__ eidx, int* __restrict__ deg) {
    int e = blockIdx.x * 256 + threadIdx.x;
    if (e < E_EDGES) atomicAdd(&deg[eidx[E_EDGES + e]], 1);
}

__global__ __launch_bounds__(256)
void k_scan1(const int* __restrict__ deg, int* __restrict__ bsum) {
    __shared__ int s[256];
    int b = blockIdx.x, t = threadIdx.x;
    int sum = 0;
#pragma unroll
    for (int i = 0; i < 4; ++i) {
        int idx = b * SCAN_CHUNK + i * 256 + t;
        sum += (idx < N_NODES) ? deg[idx] : 0;
    }
    s[t] = sum; __syncthreads();
    for (int off = 128; off > 0; off >>= 1) {
        if (t < off) s[t] += s[t + off];
        __syncthreads();
    }
    if (t == 0) bsum[b] = s[0];
}

__global__ __launch_bounds__(256)
void k_scan2(int* __restrict__ bsum, int* __restrict__ offsets) {
    __shared__ int s[256];
    int t = threadIdx.x;
    int v = (t < NB_SCAN) ? bsum[t] : 0;
    s[t] = v; __syncthreads();
    for (int off = 1; off < 256; off <<= 1) {
        int add = (t >= off) ? s[t - off] : 0;
        __syncthreads();
        s[t] += add;
        __syncthreads();
    }
    if (t < NB_SCAN) bsum[t] = s[t] - v;          // exclusive block offsets
    if (t == NB_SCAN - 1) offsets[N_NODES] = s[t]; // total (=E)
}

__global__ __launch_bounds__(256)
void k_scan3(const int* __restrict__ deg, const int* __restrict__ bsum,
             int* __restrict__ offsets) {
    __shared__ int s[256];
    int b = blockIdx.x, t = threadIdx.x;
    int base = b * SCAN_CHUNK + t * 4;
    int v[4]; int sum = 0;
#pragma unroll
    for (int i = 0; i < 4; ++i) {
        v[i] = (base + i < N_NODES) ? deg[base + i] : 0;
        sum += v[i];
    }
    s[t] = sum; __syncthreads();
    for (int off = 1; off < 256; off <<= 1) {
        int add = (t >= off) ? s[t - off] : 0;
        __syncthreads();
        s[t] += add;
        __syncthreads();
    }
    int toff = bsum[b] + s[t] - sum; // exclusive prefix for this thread's chunk
#pragma unroll
    for (int i = 0; i < 4; ++i) {
        if (base + i < N_NODES) offsets[base + i] = toff;
        toff += v[i];
    }
}

__global__ __launch_bounds__(256)
void k_fill(const int* __restrict__ eidx, const int* __restrict__ offsets,
            int* __restrict__ cursor, int* __restrict__ elist) {
    int e = blockIdx.x * 256 + threadIdx.x;
    if (e >= E_EDGES) return;
    int c = eidx[E_EDGES + e];
    int pos = atomicAdd(&cursor[c], 1);
    elist[offsets[c] + pos] = e;
}

// ---------------- Gather: wave per node, no fp32 atomics ----------------
// curl[c][h] = sum_k Q[k]*Wp[k][2h] + P[k]*Wp[k][2h+1] - b[2h]*Sdy + b[2h+1]*Sdx
// with P[k] = sum_e dx_e*ea[e][k], Q[k] = -sum_e dy_e*ea[e][k]
__global__ __launch_bounds__(256)
void k_gather(const float* __restrict__ x,
              const int* __restrict__ eidx,
              const float* __restrict__ edge_attr,
              const float* __restrict__ W_proj,
              const float* __restrict__ b_proj,
              const int* __restrict__ offsets,
              const int* __restrict__ elist,
              float* __restrict__ m_i,   // = d_out
              float* __restrict__ curl)
{
    __shared__ float Wp[HID * 8];
    for (int i = threadIdx.x; i < HID * 8; i += 256) Wp[i] = W_proj[i];
    __syncthreads();

    int wave = threadIdx.x >> 6;
    int lane = threadIdx.x & 63;
    int c = blockIdx.x * 4 + wave;
    if (c >= N_NODES) return;

    float pcx = x[(size_t)c * 130 + 128];
    float pcy = x[(size_t)c * 130 + 129];

    int jb = offsets[c], je = offsets[c + 1];

    float m0 = 0, m1 = 0, p0 = 0, p1 = 0, q0 = 0, q1 = 0, sdx = 0, sdy = 0;

    int e = 0; float prx = 0, pry = 0;
    if (jb < je) {
        e = elist[jb];
        int r = eidx[e];
        prx = x[(size_t)r * 130 + 128];
        pry = x[(size_t)r * 130 + 129];
    }
    for (int j = jb; j < je; ++j) {
        float dx = pcx - prx, dy = pcy - pry;
        float2 a = *(const float2*)(edge_attr + (size_t)e * HID + lane * 2);
        if (j + 1 < je) { // software-pipeline the dependent index chain
            int e2 = elist[j + 1];
            int r2 = eidx[e2];
            prx = x[(size_t)r2 * 130 + 128];
            pry = x[(size_t)r2 * 130 + 129];
            e = e2;
        }
        m0 += a.x;      m1 += a.y;
        p0 += a.x * dx; p1 += a.y * dx;
        q0 -= a.x * dy; q1 -= a.y * dy;
        sdx += dx;      sdy += dy;
    }

    *(float2*)(m_i + (size_t)c * HID + lane * 2) = make_float2(m0, m1);

    const float* w0 = &Wp[(2 * lane) * 8];
    const float* w1 = &Wp[(2 * lane + 1) * 8];
    float part[4];
#pragma unroll
    for (int h = 0; h < 4; ++h)
        part[h] = q0 * w0[2 * h] + p0 * w0[2 * h + 1] + q1 * w1[2 * h] + p1 * w1[2 * h + 1];
#pragma unroll
    for (int m = 1; m < 64; m <<= 1)
#pragma unroll
        for (int h = 0; h < 4; ++h) part[h] += __shfl_xor(part[h], m);

    if (lane == 0) {
#pragma unroll
        for (int h = 0; h < 4; ++h)
            curl[(size_t)c * 4 + h] = part[h] - b_proj[2 * h] * sdy + b_proj[2 * h + 1] * sdx;
    }
}

// ---------------- Node kernel: gather node_in -> GEMM1 -> LN -> SiLU -> GEMM2 ----------------
__global__ __launch_bounds__(256)
void node_kernel(const float* __restrict__ x,
                 const float* m_i,
                 const float* __restrict__ curl,
                 const float* __restrict__ u,
                 const int* __restrict__ batch,
                 const float* __restrict__ W1, const float* __restrict__ b1,
                 const float* __restrict__ ln_g, const float* __restrict__ ln_b,
                 const float* __restrict__ W2, const float* __restrict__ b2,
                 float* out)
{
    __shared__ float A[BN][392];
    int tid = threadIdx.x;
    int base = blockIdx.x * BN;

    for (int idx = tid; idx < BN * 388; idx += 256) {
        int n = idx / 388;
        int k = idx - n * 388;
        int node = base + n;
        float v = 0.f;
        if (node < N_NODES) {
            if (k < 128)       v = x[(size_t)node * 130 + k];
            else if (k < 256)  v = m_i[(size_t)node * 128 + (k - 128)];
            else if (k < 260)  v = curl[(size_t)node * 4 + (k - 256)];
            else               v = u[(size_t)batch[node] * 128 + (k - 260)];
        }
        A[n][k] = v;
    }
    __syncthreads();

    int tx = tid & 31;
    int ty = tid >> 5;

    float acc[8][4];
#pragma unroll
    for (int i = 0; i < 8; ++i)
#pragma unroll
        for (int j = 0; j < 4; ++j) acc[i][j] = 0.f;

    for (int k = 0; k < 388; ++k) {
        float4 b = *(const float4*)(W1 + (size_t)k * 128 + tx * 4);
#pragma unroll
        for (int i = 0; i < 8; ++i) {
            float a = A[ty * 8 + i][k];
            acc[i][0] += a * b.x;
            acc[i][1] += a * b.y;
            acc[i][2] += a * b.z;
            acc[i][3] += a * b.w;
        }
    }

    float4 b1v = *(const float4*)(b1 + tx * 4);
    float4 gv  = *(const float4*)(ln_g + tx * 4);
    float4 bv  = *(const float4*)(ln_b + tx * 4);
    float4 b2v = *(const float4*)(b2 + tx * 4);

    __syncthreads();
    float* S = &A[0][0];

#pragma unroll
    for (int i = 0; i < 8; ++i) {
        float h0 = acc[i][0] + b1v.x;
        float h1 = acc[i][1] + b1v.y;
        float h2 = acc[i][2] + b1v.z;
        float h3 = acc[i][3] + b1v.w;
        float s  = h0 + h1 + h2 + h3;
        float ss = h0 * h0 + h1 * h1 + h2 * h2 + h3 * h3;
#pragma unroll
        for (int m = 1; m < 32; m <<= 1) {
            s  += __shfl_xor(s, m);
            ss += __shfl_xor(ss, m);
        }
        float mu  = s * (1.f / 128.f);
        float var = ss * (1.f / 128.f) - mu * mu;
        float inv = rsqrtf(var + LN_EPS);
        h0 = (h0 - mu) * inv * gv.x + bv.x;
        h1 = (h1 - mu) * inv * gv.y + bv.y;
        h2 = (h2 - mu) * inv * gv.z + bv.z;
        h3 = (h3 - mu) * inv * gv.w + bv.w;
        h0 = h0 / (1.f + expf(-h0));
        h1 = h1 / (1.f + expf(-h1));
        h2 = h2 / (1.f + expf(-h2));
        h3 = h3 / (1.f + expf(-h3));
        *(float4*)&S[(size_t)(ty * 8 + i) * 132 + tx * 4] = make_float4(h0, h1, h2, h3);
    }
    __syncthreads();

    float acc2[8][4];
#pragma unroll
    for (int i = 0; i < 8; ++i)
#pragma unroll
        for (int j = 0; j < 4; ++j) acc2[i][j] = 0.f;

    for (int k = 0; k < 128; ++k) {
        float4 b = *(const float4*)(W2 + (size_t)k * 128 + tx * 4);
#pragma unroll
        for (int i = 0; i < 8; ++i) {
            float a = S[(size_t)(ty * 8 + i) * 132 + k];
            acc2[i][0] += a * b.x;
            acc2[i][1] += a * b.y;
            acc2[i][2] += a * b.z;
            acc2[i][3] += a * b.w;
        }
    }

#pragma unroll
    for (int i = 0; i < 8; ++i) {
        int node = base + ty * 8 + i;
        if (node < N_NODES) {
            float4 o = make_float4(acc2[i][0] + b2v.x, acc2[i][1] + b2v.y,
                                   acc2[i][2] + b2v.z, acc2[i][3] + b2v.w);
            *(float4*)(out + (size_t)node * 128 + tx * 4) = o;
        }
    }
}

extern "C" void kernel_launch(void* const* d_in, const int* in_sizes, int n_in,
                              void* d_out, int out_size, void* d_ws, size_t ws_size,
                              hipStream_t stream) {
    const float* x         = (const float*)d_in[0];
    const int*   eidx      = (const int*)d_in[1];
    const float* edge_attr = (const float*)d_in[2];
    const float* u         = (const float*)d_in[3];
    const int*   batch     = (const int*)d_in[4];
    const float* W_proj    = (const float*)d_in[5];
    const float* b_proj    = (const float*)d_in[6];
    const float* W1        = (const float*)d_in[7];
    const float* b1        = (const float*)d_in[8];
    const float* ln_g      = (const float*)d_in[9];
    const float* ln_b      = (const float*)d_in[10];
    const float* W2        = (const float*)d_in[11];
    const float* b2        = (const float*)d_in[12];

    float* out = (float*)d_out;

    // ws layout: deg(N) | cursor(N) | offsets(N+1) | bsum(256) | elist(E) | curl(N*4)
    int* deg     = (int*)d_ws;
    int* cursor  = deg + N_NODES;
    int* offsets = cursor + N_NODES;
    int* bsum    = offsets + (N_NODES + 1);
    int* elist   = bsum + 256;
    float* curl  = (float*)(elist + E_EDGES);

    hipMemsetAsync(deg, 0, (size_t)2 * N_NODES * sizeof(int), stream); // deg + cursor

    k_hist <<<(E_EDGES + 255) / 256, 256, 0, stream>>>(eidx, deg);
    k_scan1<<<NB_SCAN, 256, 0, stream>>>(deg, bsum);
    k_scan2<<<1, 256, 0, stream>>>(bsum, offsets);
    k_scan3<<<NB_SCAN, 256, 0, stream>>>(deg, bsum, offsets);
    k_fill <<<(E_EDGES + 255) / 256, 256, 0, stream>>>(eidx, offsets, cursor, elist);

    k_gather<<<(N_NODES + 3) / 4, 256, 0, stream>>>(
        x, eidx, edge_attr, W_proj, b_proj, offsets, elist, out, curl);

    node_kernel<<<(N_NODES + BN - 1) / BN, 256, 0, stream>>>(
        x, out, curl, u, batch, W1, b1, ln_g, ln_b, W2, b2, out);
}

// Round 6
// 967.993 us; speedup vs baseline: 11.8691x; 1.3147x over previous
//
#include <hip/hip_runtime.h>
#include <hip/hip_bf16.h>

#define N_NODES 100000
#define E_EDGES 1600000
#define HID 128
#define LN_EPS 1e-5f
#define SCAN_CHUNK 1024
#define NB_SCAN ((N_NODES + SCAN_CHUNK - 1) / SCAN_CHUNK)  // 98

typedef __attribute__((ext_vector_type(4))) float f32x4;

// ---------------- CSR build ----------------
__global__ __launch_bounds__(256)
void k_hist(const int* __restrict__ eidx, int* __restrict__ deg) {
    int e = blockIdx.x * 256 + threadIdx.x;
    if (e < E_EDGES) atomicAdd(&deg[eidx[E_EDGES + e]], 1);
}

__global__ __launch_bounds__(256)
void k_scan1(const int* __restrict__ deg, int* __restrict__ bsum) {
    __shared__ int s[256];
    int b = blockIdx.x, t = threadIdx.x;
    int sum = 0;
#pragma unroll
    for (int i = 0; i < 4; ++i) {
        int idx = b * SCAN_CHUNK + i * 256 + t;
        sum += (idx < N_NODES) ? deg[idx] : 0;
    }
    s[t] = sum; __syncthreads();
    for (int off = 128; off > 0; off >>= 1) {
        if (t < off) s[t] += s[t + off];
        __syncthreads();
    }
    if (t == 0) bsum[b] = s[0];
}

__global__ __launch_bounds__(256)
void k_scan2(int* __restrict__ bsum, int* __restrict__ offsets) {
    __shared__ int s[256];
    int t = threadIdx.x;
    int v = (t < NB_SCAN) ? bsum[t] : 0;
    s[t] = v; __syncthreads();
    for (int off = 1; off < 256; off <<= 1) {
        int add = (t >= off) ? s[t - off] : 0;
        __syncthreads();
        s[t] += add;
        __syncthreads();
    }
    if (t < NB_SCAN) bsum[t] = s[t] - v;
    if (t == NB_SCAN - 1) offsets[N_NODES] = s[t];
}

__global__ __launch_bounds__(256)
void k_scan3(const int* __restrict__ deg, const int* __restrict__ bsum,
             int* __restrict__ offsets) {
    __shared__ int s[256];
    int b = blockIdx.x, t = threadIdx.x;
    int base = b * SCAN_CHUNK + t * 4;
    int v[4]; int sum = 0;
#pragma unroll
    for (int i = 0; i < 4; ++i) {
        v[i] = (base + i < N_NODES) ? deg[base + i] : 0;
        sum += v[i];
    }
    s[t] = sum; __syncthreads();
    for (int off = 1; off < 256; off <<= 1) {
        int add = (t >= off) ? s[t - off] : 0;
        __syncthreads();
        s[t] += add;
        __syncthreads();
    }
    int toff = bsum[b] + s[t] - sum;
#pragma unroll
    for (int i = 0; i < 4; ++i) {
        if (base + i < N_NODES) offsets[base + i] = toff;
        toff += v[i];
    }
}

__global__ __launch_bounds__(256)
void k_fill(const int* __restrict__ eidx, const int* __restrict__ offsets,
            int* __restrict__ cursor, int* __restrict__ elist) {
    int e = blockIdx.x * 256 + threadIdx.x;
    if (e >= E_EDGES) return;
    int c = eidx[E_EDGES + e];
    int pos = atomicAdd(&cursor[c], 1);
    elist[offsets[c] + pos] = e;
}

// ---------------- Gather: wave per node, depth-2 pipelined (identical to r5) ----------------
__global__ __launch_bounds__(256)
void k_gather(const float* __restrict__ x,
              const int* __restrict__ eidx,
              const float* __restrict__ edge_attr,
              const float* __restrict__ W_proj,
              const float* __restrict__ b_proj,
              const int* __restrict__ offsets,
              const int* __restrict__ elist,
              float* m_i,
              float* __restrict__ curl)
{
    __shared__ float Wp[HID * 8];
    for (int i = threadIdx.x; i < HID * 8; i += 256) Wp[i] = W_proj[i];
    __syncthreads();

    int wave = threadIdx.x >> 6;
    int lane = threadIdx.x & 63;
    int c = blockIdx.x * 4 + wave;
    if (c >= N_NODES) return;

    float pcx = x[(size_t)c * 130 + 128];
    float pcy = x[(size_t)c * 130 + 129];

    int jb = offsets[c];
    int cnt = offsets[c + 1] - jb;

    float m0 = 0, m1 = 0, p0 = 0, p1 = 0, q0 = 0, q1 = 0, sdx = 0, sdy = 0;

    float2 aC = make_float2(0, 0), aN = make_float2(0, 0);
    float dxC = 0, dyC = 0, dxN = 0, dyN = 0;

    if (cnt > 0) {
        int e = elist[jb]; int r = eidx[e];
        dxC = pcx - x[(size_t)r * 130 + 128];
        dyC = pcy - x[(size_t)r * 130 + 129];
        aC = *(const float2*)(edge_attr + (size_t)e * HID + lane * 2);
    }
    if (cnt > 1) {
        int e = elist[jb + 1]; int r = eidx[e];
        dxN = pcx - x[(size_t)r * 130 + 128];
        dyN = pcy - x[(size_t)r * 130 + 129];
        aN = *(const float2*)(edge_attr + (size_t)e * HID + lane * 2);
    }

    for (int j = 0; j < cnt; ++j) {
        float2 a = aC; float dx = dxC, dy = dyC;
        aC = aN; dxC = dxN; dyC = dyN;
        if (j + 2 < cnt) {
            int e = elist[jb + j + 2]; int r = eidx[e];
            dxN = pcx - x[(size_t)r * 130 + 128];
            dyN = pcy - x[(size_t)r * 130 + 129];
            aN = *(const float2*)(edge_attr + (size_t)e * HID + lane * 2);
        }
        m0 += a.x;      m1 += a.y;
        p0 += a.x * dx; p1 += a.y * dx;
        q0 -= a.x * dy; q1 -= a.y * dy;
        sdx += dx;      sdy += dy;
    }

    *(float2*)(m_i + (size_t)c * HID + lane * 2) = make_float2(m0, m1);

    const float* w0 = &Wp[(2 * lane) * 8];
    const float* w1 = &Wp[(2 * lane + 1) * 8];
    float part[4];
#pragma unroll
    for (int h = 0; h < 4; ++h)
        part[h] = q0 * w0[2 * h] + p0 * w0[2 * h + 1] + q1 * w1[2 * h] + p1 * w1[2 * h + 1];
#pragma unroll
    for (int m = 1; m < 64; m <<= 1)
#pragma unroll
        for (int h = 0; h < 4; ++h) part[h] += __shfl_xor(part[h], m);

    if (lane == 0) {
#pragma unroll
        for (int h = 0; h < 4; ++h)
            curl[(size_t)c * 4 + h] = part[h] - b_proj[2 * h] * sdy + b_proj[2 * h + 1] * sdx;
    }
}

// ---------------- Node kernel BISECT: identical structure to r5 but pure fp32 VALU GEMMs ----------------
// Same staging, same curl rank-4 peel, same split-LN via pss, same epilogue mapping.
// No bf16, no W-packs, no MFMA. S stored fp32 in Af cols 0..127 (after barrier).
__global__ __launch_bounds__(256)
void node_valu(const float* __restrict__ x,
               const float* m_i,                    // aliases out (own rows only)
               const float* __restrict__ curl,
               const float* __restrict__ u,
               const int* __restrict__ batch,
               const float* __restrict__ W1,
               const float* __restrict__ b1,
               const float* __restrict__ ln_g, const float* __restrict__ ln_b,
               const float* __restrict__ W2,
               const float* __restrict__ b2,
               float* out)
{
    __shared__ float Af[32 * 396];   // [hE 0..127 | m_i 128..255 | tau 256..383]; later cols 0..127 reused for S
    __shared__ float2 pss[32][2];
    __shared__ float curl_s[32 * 4];

    const int tid = threadIdx.x;
    const int base = blockIdx.x * 32;

    for (int idx = tid; idx < 32 * 64; idx += 256) {   // h_E via float2
        int n = idx >> 6, g = idx & 63;
        int node = base + n;
        float2 v = make_float2(0.f, 0.f);
        if (node < N_NODES) v = *(const float2*)(x + (size_t)node * 130 + g * 2);
        *(float2*)&Af[n * 396 + g * 2] = v;
    }
    for (int idx = tid; idx < 32 * 32; idx += 256) {   // m_i
        int n = idx >> 5, g = idx & 31;
        int node = base + n;
        float4 v = make_float4(0.f, 0.f, 0.f, 0.f);
        if (node < N_NODES) v = *(const float4*)(m_i + (size_t)node * 128 + g * 4);
        *(float4*)&Af[n * 396 + 128 + g * 4] = v;
    }
    for (int idx = tid; idx < 32 * 32; idx += 256) {   // tau
        int n = idx >> 5, g = idx & 31;
        int node = base + n;
        float4 v = make_float4(0.f, 0.f, 0.f, 0.f);
        if (node < N_NODES) v = *(const float4*)(u + (size_t)batch[node] * 128 + g * 4);
        *(float4*)&Af[n * 396 + 256 + g * 4] = v;
    }
    for (int idx = tid; idx < 32 * 4; idx += 256) {    // curl scalar
        int node = base + (idx >> 2);
        curl_s[idx] = (node < N_NODES) ? curl[(size_t)node * 4 + (idx & 3)] : 0.f;
    }
    __syncthreads();

    const int lane = tid & 63;
    const int wave = tid >> 6;
    const int band = wave >> 1;
    const int fh   = wave & 1;
    const int cg = lane >> 4, cl = lane & 15;
    const int nl0  = band * 16 + cg * 4;

    const float* a0 = &Af[(nl0 + 0) * 396];
    const float* a1 = &Af[(nl0 + 1) * 396];
    const float* a2 = &Af[(nl0 + 2) * 396];
    const float* a3 = &Af[(nl0 + 3) * 396];

    // GEMM1: fp32 VALU, same output ownership map as the MFMA version
    f32x4 acc[4];
#pragma unroll
    for (int f = 0; f < 4; ++f) {
        int col = (fh * 4 + f) * 16 + cl;
        float s0 = 0.f, s1 = 0.f, s2 = 0.f, s3 = 0.f;
        for (int k = 0; k < 256; ++k) {
            float w = W1[(size_t)k * 128 + col];
            s0 += a0[k] * w; s1 += a1[k] * w; s2 += a2[k] * w; s3 += a3[k] * w;
        }
        for (int k = 256; k < 384; ++k) {
            float w = W1[(size_t)(k + 4) * 128 + col];
            s0 += a0[k] * w; s1 += a1[k] * w; s2 += a2[k] * w; s3 += a3[k] * w;
        }
        acc[f] = (f32x4){s0, s1, s2, s3};
    }

    // curl rank-4 update + bias (identical to r5)
#pragma unroll
    for (int f = 0; f < 4; ++f) {
        int col = (fh * 4 + f) * 16 + cl;
        float w0 = W1[(size_t)256 * 128 + col];
        float w1 = W1[(size_t)257 * 128 + col];
        float w2 = W1[(size_t)258 * 128 + col];
        float w3 = W1[(size_t)259 * 128 + col];
        float bb = b1[col];
#pragma unroll
        for (int r = 0; r < 4; ++r) {
            const float* cs = &curl_s[(nl0 + r) * 4];
            acc[f][r] += bb + cs[0] * w0 + cs[1] * w1 + cs[2] * w2 + cs[3] * w3;
        }
    }

    // LN partials (identical to r5)
    float sA[4], ssA[4];
#pragma unroll
    for (int r = 0; r < 4; ++r) {
        float s = 0.f, ss = 0.f;
#pragma unroll
        for (int f = 0; f < 4; ++f) { float h = acc[f][r]; s += h; ss += h * h; }
#pragma unroll
        for (int m = 1; m < 16; m <<= 1) {
            s  += __shfl_xor(s, m);
            ss += __shfl_xor(ss, m);
        }
        sA[r] = s; ssA[r] = ss;
    }
    if (cl == 0) {
#pragma unroll
        for (int r = 0; r < 4; ++r) pss[nl0 + r][fh] = make_float2(sA[r], ssA[r]);
    }
    __syncthreads();   // pss ready; also: all GEMM1 reads of Af complete -> safe to overwrite

    float gvv[4], bvv[4];
#pragma unroll
    for (int f = 0; f < 4; ++f) {
        int col = (fh * 4 + f) * 16 + cl;
        gvv[f] = ln_g[col]; bvv[f] = ln_b[col];
    }

#pragma unroll
    for (int r = 0; r < 4; ++r) {
        float2 p0 = pss[nl0 + r][0], p1 = pss[nl0 + r][1];
        float s = p0.x + p1.x, ss = p0.y + p1.y;
        float mu  = s * (1.f / 128.f);
        float var = ss * (1.f / 128.f) - mu * mu;
        float inv = rsqrtf(var + LN_EPS);
#pragma unroll
        for (int f = 0; f < 4; ++f) {
            float h = (acc[f][r] - mu) * inv * gvv[f] + bvv[f];
            h = h / (1.f + expf(-h));
            Af[(nl0 + r) * 396 + (fh * 4 + f) * 16 + cl] = h;   // S, fp32, in-place
        }
    }
    __syncthreads();

    // GEMM2: fp32 VALU
    f32x4 acc2[4];
#pragma unroll
    for (int f = 0; f < 4; ++f) {
        int col = (fh * 4 + f) * 16 + cl;
        float s0 = 0.f, s1 = 0.f, s2 = 0.f, s3 = 0.f;
        for (int k2 = 0; k2 < 128; ++k2) {
            float w = W2[(size_t)k2 * 128 + col];
            s0 += a0[k2] * w; s1 += a1[k2] * w; s2 += a2[k2] * w; s3 += a3[k2] * w;
        }
        acc2[f] = (f32x4){s0, s1, s2, s3};
    }

#pragma unroll
    for (int f = 0; f < 4; ++f) {
        int col = (fh * 4 + f) * 16 + cl;
        float bb = b2[col];
#pragma unroll
        for (int r = 0; r < 4; ++r) {
            int node = base + nl0 + r;
            if (node < N_NODES) out[(size_t)node * 128 + col] = acc2[f][r] + bb;
        }
    }
}

extern "C" void kernel_launch(void* const* d_in, const int* in_sizes, int n_in,
                              void* d_out, int out_size, void* d_ws, size_t ws_size,
                              hipStream_t stream) {
    const float* x         = (const float*)d_in[0];
    const int*   eidx      = (const int*)d_in[1];
    const float* edge_attr = (const float*)d_in[2];
    const float* u         = (const float*)d_in[3];
    const int*   batch     = (const int*)d_in[4];
    const float* W_proj    = (const float*)d_in[5];
    const float* b_proj    = (const float*)d_in[6];
    const float* W1        = (const float*)d_in[7];
    const float* b1        = (const float*)d_in[8];
    const float* ln_g      = (const float*)d_in[9];
    const float* ln_b      = (const float*)d_in[10];
    const float* W2        = (const float*)d_in[11];
    const float* b2        = (const float*)d_in[12];

    float* out = (float*)d_out;

    // ws carve-out: byte-identical to round 5 (W-pack sections reserved though unused this round).
    char* p = (char*)d_ws;
    size_t off = 0;
    auto take = [&](size_t bytes) {
        char* q = p + off;
        off += (bytes + 255) & ~(size_t)255;
        return q;
    };
    (void)take(49152 * 2);   // W1ph (unused this round)
    (void)take(49152 * 2);   // W1pl
    (void)take(16384 * 2);   // W2ph
    (void)take(16384 * 2);   // W2pl
    int* deg     = (int*)take(N_NODES * 4);
    int* cursor  = (int*)take(N_NODES * 4);
    int* offsets = (int*)take((N_NODES + 1) * 4);
    int* bsum    = (int*)take(256 * 4);
    int* elist   = (int*)take((size_t)E_EDGES * 4);
    float* curl  = (float*)take((size_t)N_NODES * 4 * 4);

    hipMemsetAsync(deg, 0, (size_t)N_NODES * 4, stream);
    hipMemsetAsync(cursor, 0, (size_t)N_NODES * 4, stream);

    k_hist <<<(E_EDGES + 255) / 256, 256, 0, stream>>>(eidx, deg);
    k_scan1<<<NB_SCAN, 256, 0, stream>>>(deg, bsum);
    k_scan2<<<1, 256, 0, stream>>>(bsum, offsets);
    k_scan3<<<NB_SCAN, 256, 0, stream>>>(deg, bsum, offsets);
    k_fill <<<(E_EDGES + 255) / 256, 256, 0, stream>>>(eidx, offsets, cursor, elist);

    k_gather<<<(N_NODES + 3) / 4, 256, 0, stream>>>(
        x, eidx, edge_attr, W_proj, b_proj, offsets, elist, out, curl);

    node_valu<<<(N_NODES + 31) / 32, 256, 0, stream>>>(
        x, out, curl, u, batch, W1, b1, ln_g, ln_b, W2, b2, out);
}